// Round 9
// baseline (4197.651 us; speedup 1.0000x reference)
//
#include <hip/hip_runtime.h>
#include <hip/hip_bf16.h>

#define Bn   1024
#define Tn   730
#define INn  64
#define Hn   512
#define Kn   576      // INn + Hn
#define G4n  2048     // 4*Hn

typedef __bf16 bf16x8 __attribute__((ext_vector_type(8)));
typedef float  f32x4  __attribute__((ext_vector_type(4)));

// LDS map:
//   aTile 32x576 bf16, MFMA-fragment order            : 36864 B
//   xch   kh partial-sum exchange, raw MFMA fragments  : 32768 B  (8 rg-wq x 4 cg x 64 x 16B)
//   pkBuf packed h repack, [32 rows][17 u64] (pad +1)  :  4352 B
#define XCH_OFF 36864
#define PK_OFF  (36864 + 32768)
#define PKSTR   17

// ---------------- weight pre-pack: Wc[row][k] bf16, row = gate*512+j, k over [x|h] ----------
__global__ void convert_weights(const float* __restrict__ Wih,
                                const float* __restrict__ Whh,
                                __bf16* __restrict__ Wc) {
    int idx = blockIdx.x * 256 + threadIdx.x;
    if (idx >= G4n * Kn) return;
    int row = idx / Kn;
    int k   = idx - row * Kn;
    float v = (k < INn) ? Wih[row * INn + k] : Whh[row * Hn + (k - INn)];
    Wc[idx] = (__bf16)v;
}

// fast sigmoid: v_exp + single v_rcp (error ~1ulp << bf16 h-quantization)
__device__ __forceinline__ float sigf(float x)   { return __builtin_amdgcn_rcpf(1.0f + __expf(-x)); }
__device__ __forceinline__ float tanhf_f(float x){ return 2.0f * sigf(2.0f * x) - 1.0f; }

// ---------------- persistent LSTM scan ----------------
// 256 blocks x 512 threads (8 waves), 1 block/CU. Block = (rg_i: 32 batch rows) x (cb: 64 h-cols).
// Wave role: kh = wave&1 (K-half 288), wq = wave>>1 (16 h-cols, ALL 4 gates in wreg[kb][gate]).
// OPERAND-SWAPPED MFMA (proven r7): D = mfma(W, A) -> lane owns (batch row l16,
// 4 h-cols q*4+e) for all 4 gates -> i/f/g/o in-lane, no z matrix.
// kh partials exchanged as raw fragments: 4+4 ds b128/wave, lane-contiguous (0 conflicts, r6/r7).
// NEW (r9): pk-REPACK: packed bf16 h (8B/lane) written to pkBuf (1 ds_write_b64/wave),
// sync, re-read in round-4 ownership (row r, 16 contiguous u64) -> coalesced 128B-row
// agent u64 stores (round-4's proven store path; r7's 16x32B scattered stores cost ~1us).
// Barrier: round-4 central counter VERBATIM (r8 A/B: flags regressed 3631->3959).
// COHERENCE: all cross-block data via RELAXED agent-scope atomics (write-through/bypass
// to IC); __syncthreads drains vmcnt(0) before the barrier counter bump.
__global__ __launch_bounds__(512, 1) void lstm_persist(
    const float* __restrict__ xd,     // [B,T,IN]
    const float* __restrict__ bias,   // [4H]
    const __bf16* __restrict__ Wc,    // [4H][Kn]
    __bf16* __restrict__ h0,          // [B,H] buffer A (final h lands here)
    __bf16* __restrict__ h1,          // [B,H] buffer B
    unsigned int* __restrict__ bar)   // 32 groups x 32 uints (128B stride)
{
    __shared__ __align__(16) char smem[PK_OFF + 32 * PKSTR * 8];
    bf16x8* aTile = (bf16x8*)smem;
    f32x4*  xch   = (f32x4*)(smem + XCH_OFF);
    unsigned long long* pkBuf = (unsigned long long*)(smem + PK_OFF);

    const int blk  = blockIdx.x;
    // group (rg_i) pinned to one XCD-slot (blk&7); 8 col-blocks per group
    const int rg_i = (blk & 7) * 4 + ((blk >> 3) & 3);   // 0..31 row-group
    const int cb   = blk >> 5;                           // 0..7  col-block
    const int m0   = rg_i << 5;
    const int j0   = cb << 6;

    const int tid  = threadIdx.x;              // 0..511
    const int wave = tid >> 6;                 // 0..7
    const int lane = tid & 63;
    const int q    = lane >> 4;
    const int l16  = lane & 15;

    const int kh   = wave & 1;                 // K half: kb 9*kh .. 9*kh+8
    const int wq   = wave >> 1;                // 16-col group (all 4 gates)
    const int myrg = kh;                       // row-group this wave finalizes

    // ---- resident weights: 9 kb x 4 gates for cols j0 + wq*16 + l16 (144 regs) ----
    bf16x8 wreg[9][4];
    f32x4  bq[4];
    const int wcol = j0 + wq * 16 + l16;
    #pragma unroll
    for (int cg = 0; cg < 4; ++cg) {
        #pragma unroll
        for (int kb = 0; kb < 9; ++kb)
            wreg[kb][cg] = *(const bf16x8*)(Wc + (size_t)(cg * Hn + wcol) * Kn
                                               + (kh * 9 + kb) * 32 + q * 8);
        // bias for the 4 gate-cols this lane's D elements represent: q*4+e
        bq[cg] = *(const f32x4*)(bias + cg * Hn + j0 + wq * 16 + q * 4);
    }

    // ---- c-state: 4 cells/lane: (row m0 + myrg*16 + l16, cols j0 + wq*16 + q*4 + e) ----
    float creg[4] = {0.f, 0.f, 0.f, 0.f};

    // ---- x staging: kh==0 waves, frag (xrg = wq>>1, xkb = wq&1) ----
    const bool  xown = (kh == 0);
    const float* xrb = xd + (size_t)(m0 + (wq >> 1) * 16 + l16) * (Tn * INn)
                          + (wq & 1) * 32 + q * 8;
    const int   xslot = ((wq >> 1) * 18 + (wq & 1)) * 64 + lane;

    // ---- repack ownership (store side, round-4 pattern) ----
    const int pr  = tid >> 4;                  // row 0..31
    const int pcu = tid & 15;                  // u64 col 0..15

    unsigned int* cnt = bar + (rg_i << 5);     // one 128B line per group
    bool dead = false;

    // ---- prologue: stage x(t=0) ----
    if (xown) {
        f32x4 lo = *(const f32x4*)xrb;
        f32x4 hi = *(const f32x4*)(xrb + 4);
        bf16x8 v;
        v[0] = (__bf16)lo[0]; v[1] = (__bf16)lo[1]; v[2] = (__bf16)lo[2]; v[3] = (__bf16)lo[3];
        v[4] = (__bf16)hi[0]; v[5] = (__bf16)hi[1]; v[6] = (__bf16)hi[2]; v[7] = (__bf16)hi[3];
        aTile[xslot] = v;
    }

    for (int t = 0; t < Tn; ++t) {
        const __bf16* hread  = (t & 1) ? h1 : h0;
        __bf16*       hwrite = (t & 1) ? h0 : h1;

        // ---- phase 1: h -> regs (4 u64 loads all in flight), then -> LDS ----
        unsigned long long hu[4][2];
        #pragma unroll
        for (int i = 0; i < 4; ++i) {
            const int hf  = wave * 4 + i;
            const int rg  = hf >> 4;
            const int kbh = hf & 15;
            const unsigned long long* hp = (const unsigned long long*)
                (hread + (size_t)(m0 + rg * 16 + l16) * Hn + kbh * 32 + q * 8);
            hu[i][0] = __hip_atomic_load(hp,     __ATOMIC_RELAXED, __HIP_MEMORY_SCOPE_AGENT);
            hu[i][1] = __hip_atomic_load(hp + 1, __ATOMIC_RELAXED, __HIP_MEMORY_SCOPE_AGENT);
        }
        #pragma unroll
        for (int i = 0; i < 4; ++i) {
            const int hf  = wave * 4 + i;
            const int rg  = hf >> 4;
            const int kbh = hf & 15;
            union { unsigned long long u[2]; bf16x8 v; } cv;
            cv.u[0] = hu[i][0]; cv.u[1] = hu[i][1];
            aTile[(rg * 18 + kbh + 2) * 64 + lane] = cv.v;
        }
        __syncthreads();   // #1

        // ---- phase 2: MFMA, operands swapped (W as A, activations as B) ----
        f32x4 acc0[4], acc1[4];
        const f32x4 zero = {0.f, 0.f, 0.f, 0.f};
        #pragma unroll
        for (int cg = 0; cg < 4; ++cg) {
            acc0[cg] = (kh == 0) ? bq[cg] : zero;   // bias once, in the finalizer wave
            acc1[cg] = (kh == 1) ? bq[cg] : zero;
        }
        #pragma unroll
        for (int kb = 0; kb < 9; ++kb) {
            const bf16x8 af0 = aTile[(0 * 18 + kh * 9 + kb) * 64 + lane];  // kh in ADDRESS: ok
            const bf16x8 af1 = aTile[(1 * 18 + kh * 9 + kb) * 64 + lane];
            #pragma unroll
            for (int cg = 0; cg < 4; ++cg) {
                acc0[cg] = __builtin_amdgcn_mfma_f32_16x16x32_bf16(wreg[kb][cg], af0, acc0[cg], 0, 0, 0);
                acc1[cg] = __builtin_amdgcn_mfma_f32_16x16x32_bf16(wreg[kb][cg], af1, acc1[cg], 0, 0, 0);
            }
        }
        // export the row-group the kh-partner finalizes (rule-#20: static reg indices)
        if (kh == 0) {
            #pragma unroll
            for (int cg = 0; cg < 4; ++cg)
                xch[((wq * 2 + 1) * 4 + cg) * 64 + lane] = acc1[cg];
        } else {
            #pragma unroll
            for (int cg = 0; cg < 4; ++cg)
                xch[((wq * 2 + 0) * 4 + cg) * 64 + lane] = acc0[cg];
        }
        __syncthreads();   // #2 (also: aTile reads done -> x ds_write below is safe)

        // ---- phase 3: issue x(t+1) loads; partner sum + in-lane gates under latency ----
        f32x4 xlo, xhi;
        const bool mx = xown && (t + 1 < Tn);
        if (mx) {
            const float* xp = xrb + (size_t)(t + 1) * INn;
            xlo = *(const f32x4*)xp;
            xhi = *(const f32x4*)(xp + 4);
        }
        f32x4 zs[4];
        if (kh == 0) {
            #pragma unroll
            for (int cg = 0; cg < 4; ++cg)
                zs[cg] = acc0[cg] + xch[((wq * 2 + 0) * 4 + cg) * 64 + lane];
        } else {
            #pragma unroll
            for (int cg = 0; cg < 4; ++cg)
                zs[cg] = acc1[cg] + xch[((wq * 2 + 1) * 4 + cg) * 64 + lane];
        }
        union { unsigned long long u; __bf16 h[4]; } pk;
        #pragma unroll
        for (int e = 0; e < 4; ++e) {
            const float cn = sigf(zs[1][e]) * creg[e]
                           + sigf(zs[0][e]) * tanhf_f(zs[2][e]);
            creg[e] = cn;
            pk.h[e] = (__bf16)(sigf(zs[3][e]) * tanhf_f(cn));
        }
        // repack: (row32 = myrg*16+l16, u64-col = wq*4+q), padded stride 17
        pkBuf[(myrg * 16 + l16) * PKSTR + wq * 4 + q] = pk.u;

        // finish x(t+1) staging (aTile safe after sync #2; loads had gate math to land)
        if (mx) {
            bf16x8 v;
            v[0] = (__bf16)xlo[0]; v[1] = (__bf16)xlo[1]; v[2] = (__bf16)xlo[2]; v[3] = (__bf16)xlo[3];
            v[4] = (__bf16)xhi[0]; v[5] = (__bf16)xhi[1]; v[6] = (__bf16)xhi[2]; v[7] = (__bf16)xhi[3];
            aTile[xslot] = v;
        }
        __syncthreads();   // #3: pkBuf ready

        // ---- phase 4: coalesced h store (round-4 ownership: row pr, 4 cols) ----
        const unsigned long long hv = pkBuf[pr * PKSTR + pcu];
        __hip_atomic_store((unsigned long long*)(hwrite + (size_t)(m0 + pr) * Hn + j0 + pcu * 4),
                           hv, __ATOMIC_RELAXED, __HIP_MEMORY_SCOPE_AGENT);

        // ---- phase 5: group barrier (8 blocks sharing rg_i), round-4 verbatim ----
        __syncthreads();   // #4: drains vmcnt(0): all write-through h stores at IC
        if (tid == 0) {
            __hip_atomic_fetch_add(cnt, 1u, __ATOMIC_RELAXED, __HIP_MEMORY_SCOPE_AGENT);
            if (!dead) {
                const unsigned int target = 8u * (unsigned int)(t + 1);
                int spins = 0;
                while (__hip_atomic_load(cnt, __ATOMIC_RELAXED, __HIP_MEMORY_SCOPE_AGENT) < target) {
                    __builtin_amdgcn_s_sleep(2);
                    if (++spins > 300000) { dead = true; break; }  // hang -> fast wrong-answer
                }
            }
        }
        __syncthreads();   // #5: release
    }
}

// ---------------- head: out[b] = relu(dot(h_T[b], Wl) + bl) ----------------
__global__ void head_kernel(const __bf16* __restrict__ h, const float* __restrict__ Wl,
                            const float* __restrict__ bl, float* __restrict__ out) {
    const int b = blockIdx.x;
    const int lane = threadIdx.x;  // 64 threads
    const __bf16* hp = h + (size_t)b * Hn;
    float s = 0.f;
    #pragma unroll
    for (int j = lane; j < Hn; j += 64) s += (float)hp[j] * Wl[j];
    #pragma unroll
    for (int off = 32; off > 0; off >>= 1) s += __shfl_down(s, off, 64);
    if (lane == 0) out[b] = fmaxf(s + bl[0], 0.0f);
}

extern "C" void kernel_launch(void* const* d_in, const int* in_sizes, int n_in,
                              void* d_out, int out_size, void* d_ws, size_t ws_size,
                              hipStream_t stream) {
    const float* xd  = (const float*)d_in[0];
    const float* Wih = (const float*)d_in[1];
    const float* Whh = (const float*)d_in[2];
    const float* b   = (const float*)d_in[3];
    const float* Wl  = (const float*)d_in[4];
    const float* bl  = (const float*)d_in[5];
    float* out = (float*)d_out;

    // ws layout:
    //   Wc  bf16 [2048][576] : 2,359,296 B
    //   h0  bf16 [1024][512] : 1,048,576 B
    //   h1  bf16 [1024][512] : 1,048,576 B
    //   bar u32  [32][32]    : 4,096 B
    char* ws = (char*)d_ws;
    __bf16* Wc = (__bf16*)ws;
    __bf16* h0 = (__bf16*)(ws + 2359296);
    __bf16* h1 = (__bf16*)(ws + 2359296 + 1048576);
    unsigned int* bar = (unsigned int*)(ws + 2359296 + 2 * 1048576);

    hipMemsetAsync(h0, 0, 1048576, stream);   // t=0 reads h0 as zeros
    hipMemsetAsync(bar, 0, 4096, stream);     // monotonic barrier counters (32 groups)

    const int total = G4n * Kn;
    convert_weights<<<(total + 255) / 256, 256, 0, stream>>>(Wih, Whh, Wc);

    lstm_persist<<<256, 512, 0, stream>>>(xd, b, Wc, h0, h1, bar);

    // t=729 (odd) writes h0 -> final hidden state is in h0
    head_kernel<<<Bn, 64, 0, stream>>>(h0, Wl, bl, out);
}

// Round 10
// 3637.897 us; speedup vs baseline: 1.1539x; 1.1539x over previous
//
#include <hip/hip_runtime.h>
#include <hip/hip_bf16.h>

#define Bn   1024
#define Tn   730
#define INn  64
#define Hn   512
#define Kn   576      // INn + Hn
#define G4n  2048     // 4*Hn

typedef __bf16 bf16x8 __attribute__((ext_vector_type(8)));
typedef float  f32x4  __attribute__((ext_vector_type(4)));

// Block tile: 32 batch rows x 64 h-cols (256 gate-cols), K full 576.
// A-tile: 32 x 576 bf16 in MFMA-fragment order = 36864 B.
// z exchange: [32 rows][2 khalf][256 gatecols], row stride ZROW=524 floats.
// Round-10: z-scatter is now ds_write_b128 (operand-swapped MFMA), gather unchanged.
#define ZROW   524
#define Z_OFF  36864

// ---------------- weight pre-pack: Wc[row][k] bf16, row = gate*512+j, k over [x|h] ----------
__global__ void convert_weights(const float* __restrict__ Wih,
                                const float* __restrict__ Whh,
                                __bf16* __restrict__ Wc) {
    int idx = blockIdx.x * 256 + threadIdx.x;
    if (idx >= G4n * Kn) return;
    int row = idx / Kn;
    int k   = idx - row * Kn;
    float v = (k < INn) ? Wih[row * INn + k] : Whh[row * Hn + (k - INn)];
    Wc[idx] = (__bf16)v;
}

// fast sigmoid: v_exp + single v_rcp (error ~1ulp << bf16 h-quantization)
__device__ __forceinline__ float sigf(float x)   { return __builtin_amdgcn_rcpf(1.0f + __expf(-x)); }
__device__ __forceinline__ float tanhf_f(float x){ return 2.0f * sigf(2.0f * x) - 1.0f; }

// ---------------- persistent LSTM scan ----------------
// ROUND-4 TRUNK (3631us) + two subtractive changes:
// (1) OPERAND-SWAPPED MFMA: D = mfma(W_frag, A_frag). D rows = gate-cols (q*4+e),
//     D cols = batch rows (l16). Each acc[rg][cg] f32x4 = 4 consecutive gate-cols of
//     one batch row -> z-scatter = 8 ds_write_b128/wave (was 32 ds_write_b32).
//     Gather/pointwise/coalesced-u64-store side is r4 VERBATIM (same zT addressing).
//     Fragment symmetry validated end-to-end in r7/r9 (both passed).
// (2) ALL-THREAD SPIN barrier (3 syncs/step, was 4): every thread polls the central
//     counter (wave-coalesced broadcast load of one line); release-sync deleted —
//     waves self-release into their h-loads, sync#1 re-aligns. Same counter, same
//     fetch_add, same drain sync -> same ordering guarantee as r4.
// COHERENCE: all cross-block data via RELAXED agent-scope atomics (write-through/
// bypass to IC); __syncthreads drains vmcnt(0) before the barrier counter bump.
__global__ __launch_bounds__(512, 1) void lstm_persist(
    const float* __restrict__ xd,     // [B,T,IN]
    const float* __restrict__ bias,   // [4H]
    const __bf16* __restrict__ Wc,    // [4H][Kn]
    __bf16* __restrict__ h0,          // [B,H] buffer A (final h lands here)
    __bf16* __restrict__ h1,          // [B,H] buffer B
    unsigned int* __restrict__ bar)   // 32 groups x 32 uints (128B stride)
{
    // LDS: A-tile 36864 B + z 32*524*4 = 67072 B -> 103936 B (1 block/CU)
    __shared__ __align__(16) char smem[Z_OFF + ZROW * 32 * 4];
    bf16x8* aTile = (bf16x8*)smem;
    float*  zT    = (float*)(smem + Z_OFF);

    const int blk  = blockIdx.x;
    // group (rg_i) pinned to one XCD-slot (blk&7); 8 col-blocks per group
    const int rg_i = (blk & 7) * 4 + ((blk >> 3) & 3);   // 0..31 row-group
    const int cb   = blk >> 5;                           // 0..7  col-block
    const int m0   = rg_i << 5;
    const int j0   = cb << 6;

    const int tid  = threadIdx.x;              // 0..511
    const int wave = tid >> 6;                 // 0..7
    const int lane = tid & 63;
    const int q    = lane >> 4;
    const int l16  = lane & 15;

    const int kh = wave & 1;                   // K half: kb 9*kh .. 9*kh+8
    const int cq = wave >> 1;                  // gate-col quarter (64 of 256)

    // ---- resident weights: 9 kb x 4 colgroups; gcg = cq*4+cg -> gate = gcg>>2 ----
    // W-frag (A-operand of swapped mfma): 16 "rows" = gate-cols (l16), k = q*8..
    bf16x8 wreg[9][4];
    f32x4  bq[4];
    #pragma unroll
    for (int cg = 0; cg < 4; ++cg) {
        const int gcg  = cq * 4 + cg;
        const int gate = gcg >> 2;
        const int col  = j0 + (gcg & 3) * 16 + l16;
        #pragma unroll
        for (int kb = 0; kb < 9; ++kb)
            wreg[kb][cg] = *(const bf16x8*)(Wc + (size_t)(gate * Hn + col) * Kn
                                               + (kh * 9 + kb) * 32 + q * 8);
        // bias for this lane's D elements: gate-cols (gcg&3)*16 + q*4 + e
        bq[cg] = (kh == 0)
               ? *(const f32x4*)(bias + gate * Hn + j0 + (gcg & 3) * 16 + q * 4)
               : (f32x4){0.f, 0.f, 0.f, 0.f};
    }

    // ---- pointwise ownership: thread -> (row r of 32, 4 consecutive cols) ----
    const int r  = tid >> 4;                   // 0..31
    const int c4 = (tid & 15) << 2;            // 0..60
    float creg[4] = {0.f, 0.f, 0.f, 0.f};

    // ---- x staging: threads 0..255, frag f = tid>>6 (rg = f>>1, kb = f&1) ----
    const int xt    = tid & 255;
    const int xrg   = (xt >> 7) & 1;
    const int xkb   = (xt >> 6) & 1;
    const int xlane = xt & 63;
    const int xq    = xlane >> 4;
    const int xl16  = xlane & 15;
    const float* xrb = xd + (size_t)(m0 + xrg * 16 + xl16) * (Tn * INn) + xkb * 32 + xq * 8;
    const int xslot  = (xrg * 18 + xkb) * 64 + xlane;
    const bool xown  = (tid < 256);

    unsigned int* cnt = bar + (rg_i << 5);     // one 128B line per group
    bool dead = false;

    // ---- prologue: stage x(t=0) ----
    if (xown) {
        f32x4 lo = *(const f32x4*)xrb;
        f32x4 hi = *(const f32x4*)(xrb + 4);
        bf16x8 v;
        v[0] = (__bf16)lo[0]; v[1] = (__bf16)lo[1]; v[2] = (__bf16)lo[2]; v[3] = (__bf16)lo[3];
        v[4] = (__bf16)hi[0]; v[5] = (__bf16)hi[1]; v[6] = (__bf16)hi[2]; v[7] = (__bf16)hi[3];
        aTile[xslot] = v;
    }

    for (int t = 0; t < Tn; ++t) {
        const __bf16* hread  = (t & 1) ? h1 : h0;
        __bf16*       hwrite = (t & 1) ? h0 : h1;

        // ---- phase 0: all-thread spin on the group counter (self-release) ----
        if (t > 0 && !dead) {
            const unsigned int tgt = 8u * (unsigned int)t;
            int spins = 0;
            while (__hip_atomic_load(cnt, __ATOMIC_RELAXED, __HIP_MEMORY_SCOPE_AGENT) < tgt) {
                __builtin_amdgcn_s_sleep(2);
                if (++spins > 300000) { dead = true; break; }   // hang -> fast wrong-answer
            }
        }

        // ---- phase 1: h -> regs (4 u64 loads all in flight), then -> LDS ----
        unsigned long long hu[4][2];
        #pragma unroll
        for (int i = 0; i < 4; ++i) {
            const int hf  = wave * 4 + i;
            const int rg  = hf >> 4;
            const int kbh = hf & 15;
            const unsigned long long* hp = (const unsigned long long*)
                (hread + (size_t)(m0 + rg * 16 + l16) * Hn + kbh * 32 + q * 8);
            hu[i][0] = __hip_atomic_load(hp,     __ATOMIC_RELAXED, __HIP_MEMORY_SCOPE_AGENT);
            hu[i][1] = __hip_atomic_load(hp + 1, __ATOMIC_RELAXED, __HIP_MEMORY_SCOPE_AGENT);
        }
        #pragma unroll
        for (int i = 0; i < 4; ++i) {
            const int hf  = wave * 4 + i;
            const int rg  = hf >> 4;
            const int kbh = hf & 15;
            union { unsigned long long u[2]; bf16x8 v; } cv;
            cv.u[0] = hu[i][0]; cv.u[1] = hu[i][1];
            aTile[(rg * 18 + kbh + 2) * 64 + lane] = cv.v;
        }
        __syncthreads();   // #1: A-tile ready (also re-aligns self-released waves)

        // ---- phase 2: MFMA, operands swapped; A-frag = activations as B-operand ----
        f32x4 acc[2][4];
        #pragma unroll
        for (int rg = 0; rg < 2; ++rg)
            #pragma unroll
            for (int cg = 0; cg < 4; ++cg)
                acc[rg][cg] = bq[cg];
        #pragma unroll
        for (int kb = 0; kb < 9; ++kb) {
            const bf16x8 af0 = aTile[(0 * 18 + kh * 9 + kb) * 64 + lane];
            const bf16x8 af1 = aTile[(1 * 18 + kh * 9 + kb) * 64 + lane];
            #pragma unroll
            for (int cg = 0; cg < 4; ++cg) {
                acc[0][cg] = __builtin_amdgcn_mfma_f32_16x16x32_bf16(wreg[kb][cg], af0, acc[0][cg], 0, 0, 0);
                acc[1][cg] = __builtin_amdgcn_mfma_f32_16x16x32_bf16(wreg[kb][cg], af1, acc[1][cg], 0, 0, 0);
            }
        }
        // z scatter (b128): batchrow = rg*16 + l16; gatecols (cq*4+cg)*16 + q*4 .. +3
        #pragma unroll
        for (int rg = 0; rg < 2; ++rg)
            #pragma unroll
            for (int cg = 0; cg < 4; ++cg)
                *(f32x4*)&zT[(rg * 16 + l16) * ZROW + kh * 256 + (cq * 4 + cg) * 16 + q * 4]
                    = acc[rg][cg];
        __syncthreads();   // #2: z ready; aTile reads done -> x ds_write below safe

        // ---- phase 3: issue x(t+1) loads; pointwise under their latency ----
        f32x4 xlo, xhi;
        const bool mx = xown && (t + 1 < Tn);
        if (mx) {
            const float* xp = xrb + (size_t)(t + 1) * INn;
            xlo = *(const f32x4*)xp;
            xhi = *(const f32x4*)(xp + 4);
        }

        // gate pointwise: f32x4 gather of both K-halves, sum, activate (r4 verbatim)
        float zg[4][4];
        #pragma unroll
        for (int g = 0; g < 4; ++g) {
            f32x4 v0 = *(const f32x4*)&zT[r * ZROW +       g * 64 + c4];
            f32x4 v1 = *(const f32x4*)&zT[r * ZROW + 256 + g * 64 + c4];
            f32x4 s  = v0 + v1;
            zg[g][0] = s[0]; zg[g][1] = s[1]; zg[g][2] = s[2]; zg[g][3] = s[3];
        }
        union { unsigned long long u; __bf16 h[4]; } pk;
        #pragma unroll
        for (int cc = 0; cc < 4; ++cc) {
            const float cn = sigf(zg[1][cc]) * creg[cc]
                           + sigf(zg[0][cc]) * tanhf_f(zg[2][cc]);
            creg[cc] = cn;
            pk.h[cc] = (__bf16)(sigf(zg[3][cc]) * tanhf_f(cn));
        }
        __hip_atomic_store((unsigned long long*)(hwrite + (size_t)(m0 + r) * Hn + j0 + c4),
                           pk.u, __ATOMIC_RELAXED, __HIP_MEMORY_SCOPE_AGENT);

        // finish x(t+1) staging (loads have had the gate math to land)
        if (mx) {
            bf16x8 v;
            v[0] = (__bf16)xlo[0]; v[1] = (__bf16)xlo[1]; v[2] = (__bf16)xlo[2]; v[3] = (__bf16)xlo[3];
            v[4] = (__bf16)xhi[0]; v[5] = (__bf16)xhi[1]; v[6] = (__bf16)xhi[2]; v[7] = (__bf16)xhi[3];
            aTile[xslot] = v;
        }

        // ---- phase 4: drain + bump (no release sync; next iter self-releases) ----
        __syncthreads();   // #3: drains vmcnt(0): all write-through h stores at IC;
                           //     also LDS fence before next iter's phase-1 writes
        if (tid == 0)
            __hip_atomic_fetch_add(cnt, 1u, __ATOMIC_RELAXED, __HIP_MEMORY_SCOPE_AGENT);
    }
}

// ---------------- head: out[b] = relu(dot(h_T[b], Wl) + bl) ----------------
__global__ void head_kernel(const __bf16* __restrict__ h, const float* __restrict__ Wl,
                            const float* __restrict__ bl, float* __restrict__ out) {
    const int b = blockIdx.x;
    const int lane = threadIdx.x;  // 64 threads
    const __bf16* hp = h + (size_t)b * Hn;
    float s = 0.f;
    #pragma unroll
    for (int j = lane; j < Hn; j += 64) s += (float)hp[j] * Wl[j];
    #pragma unroll
    for (int off = 32; off > 0; off >>= 1) s += __shfl_down(s, off, 64);
    if (lane == 0) out[b] = fmaxf(s + bl[0], 0.0f);
}

extern "C" void kernel_launch(void* const* d_in, const int* in_sizes, int n_in,
                              void* d_out, int out_size, void* d_ws, size_t ws_size,
                              hipStream_t stream) {
    const float* xd  = (const float*)d_in[0];
    const float* Wih = (const float*)d_in[1];
    const float* Whh = (const float*)d_in[2];
    const float* b   = (const float*)d_in[3];
    const float* Wl  = (const float*)d_in[4];
    const float* bl  = (const float*)d_in[5];
    float* out = (float*)d_out;

    // ws layout:
    //   Wc  bf16 [2048][576] : 2,359,296 B
    //   h0  bf16 [1024][512] : 1,048,576 B
    //   h1  bf16 [1024][512] : 1,048,576 B
    //   bar u32  [32][32]    : 4,096 B
    char* ws = (char*)d_ws;
    __bf16* Wc = (__bf16*)ws;
    __bf16* h0 = (__bf16*)(ws + 2359296);
    __bf16* h1 = (__bf16*)(ws + 2359296 + 1048576);
    unsigned int* bar = (unsigned int*)(ws + 2359296 + 2 * 1048576);

    hipMemsetAsync(h0, 0, 1048576, stream);   // t=0 reads h0 as zeros
    hipMemsetAsync(bar, 0, 4096, stream);     // monotonic barrier counters (32 groups)

    const int total = G4n * Kn;
    convert_weights<<<(total + 255) / 256, 256, 0, stream>>>(Wih, Whh, Wc);

    lstm_persist<<<256, 512, 0, stream>>>(xd, b, Wc, h0, h1, bar);

    // t=729 (odd) writes h0 -> final hidden state is in h0
    head_kernel<<<Bn, 64, 0, stream>>>(h0, Wl, bl, out);
}